// Round 1
// baseline (941.979 us; speedup 1.0000x reference)
//
#include <hip/hip_runtime.h>

#define LARGE_F 1e30f

constexpr int BB = 128;
constexpr int NN = 512;
constexpr int MM = 512;
constexpr int KK = 64;
constexpr int NDIAG = NN + MM - 1;   // 1023
constexpr int CELLS = NN * MM;       // 262144 per batch

// Number of cells in antidiagonals 0..p-1 (compact antidiagonal layout offset).
__device__ __forceinline__ int diag_off(int p) {
    return (p < NN) ? (p * (p + 1)) / 2
                    : CELLS - ((NDIAG - p) * (NDIAG - p + 1)) / 2;
}

// ---------------- Phase 1: D[b,i,j] = ||x_i - y_j||^2, written in compact
// antidiagonal layout: Dws[b*CELLS + diag_off(i+j) + (i - max(0, i+j-(MM-1)))]
__global__ __launch_bounds__(256) void sdtw_dist(const float* __restrict__ x,
                                                 const float* __restrict__ y,
                                                 float* __restrict__ Dws) {
    __shared__ float xs[64][68];   // pad to 68 floats: 16B-aligned rows, benign banks
    __shared__ float ys[64][68];
    __shared__ float x2s[64];
    __shared__ float y2s[64];

    const int b  = blockIdx.y;
    const int ti = (blockIdx.x >> 3) << 6;   // tile row origin
    const int tj = (blockIdx.x & 7) << 6;    // tile col origin
    const int t  = threadIdx.x;

    const float* xb = x + ((size_t)b * NN + ti) * KK;
    const float* yb = y + ((size_t)b * MM + tj) * KK;

    // Stage 64x64 tiles of x and y (coalesced float4 loads).
    {
        const int r0 = t >> 4;          // 0..15
        const int c0 = (t & 15) << 2;   // 0..60
#pragma unroll
        for (int q = 0; q < 4; ++q) {
            const int r = r0 + (q << 4);
            const float4 xv = *(const float4*)(xb + r * KK + c0);
            const float4 yv = *(const float4*)(yb + r * KK + c0);
            *(float4*)(&xs[r][c0]) = xv;
            *(float4*)(&ys[r][c0]) = yv;
        }
    }
    __syncthreads();

    // Row squared norms.
    if (t < 128) {
        const int r = t & 63;
        const float* row = (t < 64) ? &xs[r][0] : &ys[r][0];
        float s = 0.f;
#pragma unroll
        for (int k = 0; k < KK; k += 4) {
            const float4 v = *(const float4*)(row + k);
            s = fmaf(v.x, v.x, s); s = fmaf(v.y, v.y, s);
            s = fmaf(v.z, v.z, s); s = fmaf(v.w, v.w, s);
        }
        if (t < 64) x2s[r] = s; else y2s[r] = s;
    }
    __syncthreads();

    // 4x4 microtile, strided mapping: rows a*16+ty, cols c*16+tx.
    // x-reads are wave-uniform (broadcast), y-reads are 2-way (free).
    const int ty = t >> 4;   // 0..15
    const int tx = t & 15;   // 0..15

    float acc[4][4] = {};
    for (int k0 = 0; k0 < KK; k0 += 4) {
        float4 xa[4], yv[4];
#pragma unroll
        for (int a = 0; a < 4; ++a) xa[a] = *(const float4*)(&xs[(a << 4) + ty][k0]);
#pragma unroll
        for (int c = 0; c < 4; ++c) yv[c] = *(const float4*)(&ys[(c << 4) + tx][k0]);
#pragma unroll
        for (int a = 0; a < 4; ++a) {
#pragma unroll
            for (int c = 0; c < 4; ++c) {
                acc[a][c] = fmaf(xa[a].x, yv[c].x, acc[a][c]);
                acc[a][c] = fmaf(xa[a].y, yv[c].y, acc[a][c]);
                acc[a][c] = fmaf(xa[a].z, yv[c].z, acc[a][c]);
                acc[a][c] = fmaf(xa[a].w, yv[c].w, acc[a][c]);
            }
        }
    }

    float* Db = Dws + (size_t)b * CELLS;
#pragma unroll
    for (int a = 0; a < 4; ++a) {
        const int i  = ti + (a << 4) + ty;
        const float xx = x2s[(a << 4) + ty];
#pragma unroll
        for (int c = 0; c < 4; ++c) {
            const int j = tj + (c << 4) + tx;
            const int p = i + j;
            const int imin = (p - (MM - 1)) > 0 ? (p - (MM - 1)) : 0;
            const float d = xx + y2s[(c << 4) + tx] - 2.f * acc[a][c];
            Db[diag_off(p) + (i - imin)] = d;
        }
    }
}

// ---------------- Phase 2: soft-DTW DP over antidiagonals.
// One block per batch, thread i owns row i. Rotating LDS rows; one barrier/step.
__global__ __launch_bounds__(512) void sdtw_dp(const float* __restrict__ Dws,
                                               float* __restrict__ out) {
    __shared__ float rbuf[3][NN];
    const int b = blockIdx.x;
    const int i = threadIdx.x;
    const float* Db = Dws + (size_t)b * CELLS;

    rbuf[0][i] = LARGE_F;
    rbuf[1][i] = LARGE_F;
    rbuf[2][i] = LARGE_F;

    // Depth-2 register prefetch of D antidiagonal rows (contiguous, coalesced).
    float dg0 = 0.f, dg1 = 0.f;
    if (i == 0) dg0 = Db[0];
    if (i <= 1) dg1 = Db[1 + i];

    float* row_w  = rbuf[0];   // write slot (p)
    float* row_p  = rbuf[2];   // p-1
    float* row_p2 = rbuf[1];   // p-2

    __syncthreads();

    float cur = LARGE_F;
    for (int p = 0; p < NDIAG; ++p) {
        // prefetch diagonal p+2
        float dg2 = 0.f;
        const int p2 = p + 2;
        if (p2 < NDIAG) {
            const int imin2 = (p2 - (MM - 1)) > 0 ? (p2 - (MM - 1)) : 0;
            const int imax2 = (p2 < NN - 1) ? p2 : (NN - 1);
            if (i >= imin2 && i <= imax2) dg2 = Db[diag_off(p2) + (i - imin2)];
        }

        const int j0 = p - i;
        const bool valid = (j0 >= 0) && (j0 < MM);

        const float r_w  = row_p[i];
        const float r_n  = (i > 0) ? row_p[i - 1] : LARGE_F;
        const float r_nw = (i > 0) ? row_p2[i - 1] : ((p == 0) ? 0.f : LARGE_F);

        const float m = fminf(fminf(r_nw, r_n), r_w);
        const float s = __expf(m - r_nw) + __expf(m - r_n) + __expf(m - r_w);
        const float softmin = m - __logf(s);

        cur = valid ? (dg0 + softmin) : LARGE_F;
        row_w[i] = cur;
        __syncthreads();

        float* tmp = row_w;
        row_w = row_p2; row_p2 = row_p; row_p = tmp;
        dg0 = dg1; dg1 = dg2;
    }
    if (i == NN - 1) out[b] = cur;
}

// ---------------- Fallback (only if ws_size < 134.2 MB): fused, recompute
// distances from global y per cell. Slow but correct; distinct name for rocprof.
__global__ __launch_bounds__(512) void sdtw_fused_naive(const float* __restrict__ x,
                                                        const float* __restrict__ y,
                                                        float* __restrict__ out) {
    __shared__ float rbuf[3][NN];
    __shared__ float y2s[MM];
    const int b = blockIdx.x;
    const int i = threadIdx.x;

    const float* xrow  = x + ((size_t)b * NN + i) * KK;
    const float* ybase = y + (size_t)b * MM * KK;

    float xr[KK];
    float x2 = 0.f;
#pragma unroll
    for (int k = 0; k < KK; k += 4) {
        const float4 v = *(const float4*)(xrow + k);
        xr[k] = v.x; xr[k + 1] = v.y; xr[k + 2] = v.z; xr[k + 3] = v.w;
        x2 = fmaf(v.x, v.x, fmaf(v.y, v.y, fmaf(v.z, v.z, fmaf(v.w, v.w, x2))));
    }
    {
        const float* yrow = ybase + (size_t)i * KK;
        float s = 0.f;
#pragma unroll
        for (int k = 0; k < KK; k += 4) {
            const float4 v = *(const float4*)(yrow + k);
            s = fmaf(v.x, v.x, s); s = fmaf(v.y, v.y, s);
            s = fmaf(v.z, v.z, s); s = fmaf(v.w, v.w, s);
        }
        y2s[i] = s;
    }
    rbuf[0][i] = LARGE_F;
    rbuf[1][i] = LARGE_F;
    rbuf[2][i] = LARGE_F;

    float* row_w  = rbuf[0];
    float* row_p  = rbuf[2];
    float* row_p2 = rbuf[1];
    __syncthreads();

    float cur = LARGE_F;
    for (int p = 0; p < NDIAG; ++p) {
        const int j0 = p - i;
        const bool valid = (j0 >= 0) && (j0 < MM);
        float dg = 0.f;
        if (valid) {
            const float* yrow = ybase + (size_t)j0 * KK;
            float dot = 0.f;
#pragma unroll
            for (int k = 0; k < KK; k += 4) {
                const float4 v = *(const float4*)(yrow + k);
                dot = fmaf(xr[k], v.x, dot);
                dot = fmaf(xr[k + 1], v.y, dot);
                dot = fmaf(xr[k + 2], v.z, dot);
                dot = fmaf(xr[k + 3], v.w, dot);
            }
            dg = x2 + y2s[j0] - 2.f * dot;
        }
        const float r_w  = row_p[i];
        const float r_n  = (i > 0) ? row_p[i - 1] : LARGE_F;
        const float r_nw = (i > 0) ? row_p2[i - 1] : ((p == 0) ? 0.f : LARGE_F);

        const float m = fminf(fminf(r_nw, r_n), r_w);
        const float s = __expf(m - r_nw) + __expf(m - r_n) + __expf(m - r_w);
        const float softmin = m - __logf(s);

        cur = valid ? (dg + softmin) : LARGE_F;
        row_w[i] = cur;
        __syncthreads();

        float* tmp = row_w;
        row_w = row_p2; row_p2 = row_p; row_p = tmp;
    }
    if (i == NN - 1) out[b] = cur;
}

extern "C" void kernel_launch(void* const* d_in, const int* in_sizes, int n_in,
                              void* d_out, int out_size, void* d_ws, size_t ws_size,
                              hipStream_t stream) {
    const float* x = (const float*)d_in[0];
    const float* y = (const float*)d_in[1];
    float* out = (float*)d_out;

    const size_t need = (size_t)BB * CELLS * sizeof(float);  // 134,217,728 B
    if (ws_size >= need) {
        float* Dws = (float*)d_ws;
        sdtw_dist<<<dim3(64, BB), 256, 0, stream>>>(x, y, Dws);
        sdtw_dp<<<dim3(BB), 512, 0, stream>>>(Dws, out);
    } else {
        sdtw_fused_naive<<<dim3(BB), 512, 0, stream>>>(x, y, out);
    }
}

// Round 2
// 791.227 us; speedup vs baseline: 1.1905x; 1.1905x over previous
//
#include <hip/hip_runtime.h>

#define LARGE_F 1e30f
#define LOG2E_F 1.4426950408889634f
#define LN2_F   0.6931471805599453f

constexpr int BB = 128;
constexpr int NN = 512;
constexpr int MM = 512;
constexpr int KK = 64;
constexpr int NDIAG = NN + MM - 1;   // 1023
constexpr int CELLS = NN * MM;       // 262144 per batch

// Cells in antidiagonals 0..p-1 (compact antidiagonal layout offset).
__device__ __forceinline__ int diag_off(int p) {
    return (p < NN) ? (p * (p + 1)) / 2
                    : CELLS - ((NDIAG - p) * (NDIAG - p + 1)) / 2;
}
__device__ __forceinline__ int diag_imin(int p) {
    return (p > MM - 1) ? (p - (MM - 1)) : 0;
}

// ---------------- Phase 1: D[b,i,j] = ||x_i - y_j||^2 in compact antidiagonal
// layout. D-tile staged in LDS (aliased onto xs), written out as contiguous
// per-diagonal runs -> coalesced stores (fixes the 7.4x write amplification).
__global__ __launch_bounds__(256, 4) void sdtw_dist(const float* __restrict__ x,
                                                    const float* __restrict__ y,
                                                    float* __restrict__ Dws) {
    __shared__ float xs[64][68];
    __shared__ float ys[64][68];
    __shared__ float x2s[64];
    __shared__ float y2s[64];
    // D tile aliases xs after the k-loop (4224 <= 4352 floats). Pad 66 so
    // diagonal reads (addr = 65*i + q) have bank stride 65 % 32 = 1.
    float (*dt)[66] = (float (*)[66])(&xs[0][0]);

    const int b  = blockIdx.y;
    const int ti = (blockIdx.x >> 3) << 6;
    const int tj = (blockIdx.x & 7) << 6;
    const int t  = threadIdx.x;

    const float* xb = x + ((size_t)b * NN + ti) * KK;
    const float* yb = y + ((size_t)b * MM + tj) * KK;

    {
        const int r0 = t >> 4;
        const int c0 = (t & 15) << 2;
#pragma unroll
        for (int q = 0; q < 4; ++q) {
            const int r = r0 + (q << 4);
            const float4 xv = *(const float4*)(xb + r * KK + c0);
            const float4 yv = *(const float4*)(yb + r * KK + c0);
            *(float4*)(&xs[r][c0]) = xv;
            *(float4*)(&ys[r][c0]) = yv;
        }
    }
    __syncthreads();

    if (t < 128) {
        const int r = t & 63;
        const float* row = (t < 64) ? &xs[r][0] : &ys[r][0];
        float s = 0.f;
#pragma unroll
        for (int k = 0; k < KK; k += 4) {
            const float4 v = *(const float4*)(row + k);
            s = fmaf(v.x, v.x, s); s = fmaf(v.y, v.y, s);
            s = fmaf(v.z, v.z, s); s = fmaf(v.w, v.w, s);
        }
        if (t < 64) x2s[r] = s; else y2s[r] = s;
    }
    __syncthreads();

    const int ty = t >> 4;   // 0..15
    const int tx = t & 15;   // 0..15

    float acc[4][4] = {};
    for (int k0 = 0; k0 < KK; k0 += 4) {
        float4 xa[4], yv[4];
#pragma unroll
        for (int a = 0; a < 4; ++a) xa[a] = *(const float4*)(&xs[(a << 4) + ty][k0]);
#pragma unroll
        for (int c = 0; c < 4; ++c) yv[c] = *(const float4*)(&ys[(c << 4) + tx][k0]);
#pragma unroll
        for (int a = 0; a < 4; ++a) {
#pragma unroll
            for (int c = 0; c < 4; ++c) {
                acc[a][c] = fmaf(xa[a].x, yv[c].x, acc[a][c]);
                acc[a][c] = fmaf(xa[a].y, yv[c].y, acc[a][c]);
                acc[a][c] = fmaf(xa[a].z, yv[c].z, acc[a][c]);
                acc[a][c] = fmaf(xa[a].w, yv[c].w, acc[a][c]);
            }
        }
    }
    __syncthreads();   // everyone done reading xs -> safe to alias as dt

    // Stage D tile in LDS.
#pragma unroll
    for (int a = 0; a < 4; ++a) {
        const float xx = x2s[(a << 4) + ty];
#pragma unroll
        for (int c = 0; c < 4; ++c) {
            dt[(a << 4) + ty][(c << 4) + tx] = xx + y2s[(c << 4) + tx] - 2.f * acc[a][c];
        }
    }
    __syncthreads();

    // Diagonal-ordered write-out: each tile diagonal is one contiguous run.
    {
        const int w    = t >> 6;   // wave 0..3
        const int lane = t & 63;
        float* Db = Dws + (size_t)b * CELLS;
        for (int q = w; q < 127; q += 4) {
            const int i_lo = (q > 63) ? (q - 63) : 0;
            const int i_hi = (q < 63) ? q : 63;
            const int len  = i_hi - i_lo + 1;
            if (lane < len) {
                const int il = i_lo + lane;
                const int p  = ti + tj + q;
                Db[diag_off(p) + (ti + il - diag_imin(p))] = dt[il][q - il];
            }
        }
    }
}

// ---------------- Phase 2: soft-DTW DP, one wave per batch, 8 rows/lane,
// all state in registers; 2 shuffles/step, zero barriers, zero LDS.
// Works in log2e-scaled domain: softmin' = min3 - log2(1 + 2^(mn-md) + 2^(mn-mx)).
__global__ __launch_bounds__(64) void sdtw_dp(const float* __restrict__ Dws,
                                              float* __restrict__ out) {
    const int b    = blockIdx.x;
    const int lane = threadIdx.x;
    const float* __restrict__ Db = Dws + (size_t)b * CELLS;

    float A[8], B[8];          // ping-pong diagonal states (R_{p-1}, R_{p-2})
    float dEven[8], dOdd[8];   // prefetched D for even / odd diagonals
#pragma unroll
    for (int c = 0; c < 8; ++c) { A[c] = LARGE_F; B[c] = LARGE_F; }

    // Preload diagonals 0 and 1 (loads are provably in-bounds for all lanes).
    {
        const float* d0 = Db + (diag_off(0) - diag_imin(0));
        const float* d1 = Db + (diag_off(1) - diag_imin(1));
#pragma unroll
        for (int c = 0; c < 8; ++c) {
            dEven[c] = d0[8 * lane + c];
            dOdd[c]  = d1[8 * lane + c];
        }
    }

    auto dp_step = [&](int p_, float (&PREV)[8], float (&PREV2)[8], float (&DBUF)[8]) {
        // Boundary values from the lane above (row 8*lane - 1).
        float shp  = __shfl_up(PREV[7], 1);
        float shp2 = __shfl_up(PREV2[7], 1);
        if (lane == 0) { shp = LARGE_F; shp2 = (p_ == 0) ? 0.f : LARGE_F; }
        // Descending c: PREV2[c] can be overwritten in place (new R_p).
#pragma unroll
        for (int c = 7; c >= 0; --c) {
            const int i = 8 * lane + c;
            const float r_w  = PREV[c];
            const float r_n  = (c == 0) ? shp  : PREV[c - 1];
            const float r_nw = (c == 0) ? shp2 : PREV2[c - 1];
            const float mn = fminf(fminf(r_w, r_n), r_nw);
            const float mx = fmaxf(fmaxf(r_w, r_n), r_nw);
            const float md = __builtin_amdgcn_fmed3f(r_w, r_n, r_nw);
            const float s  = 1.0f + exp2f(mn - md) + exp2f(mn - mx);
            const float sm = mn - log2f(s);
            const float cur = fmaf(DBUF[c], LOG2E_F, sm);
            PREV2[c] = ((unsigned)(p_ - i) < (unsigned)MM) ? cur : LARGE_F;
        }
        // Refill DBUF with diagonal p+2 (consumed two steps from now).
        const int pn = p_ + 2;
        if (pn < NDIAG) {
            const float* __restrict__ dn = Db + (diag_off(pn) - diag_imin(pn));
#pragma unroll
            for (int c = 0; c < 8; ++c) DBUF[c] = dn[8 * lane + c];
        }
    };

#pragma unroll 1
    for (int p = 0; p < 1024; p += 2) {
        dp_step(p,     A, B, dEven);   // writes R_p     into B
        dp_step(p + 1, B, A, dOdd);    // writes R_{p+1} into A
    }
    // After the final pair, B holds R_1022; cell (511,511) is lane 63, c=7.
    if (lane == 63) out[b] = B[7] * LN2_F;
}

// ---------------- Fallback (only if ws_size < 134.2 MB): fused, correct, slow.
__global__ __launch_bounds__(512) void sdtw_fused_naive(const float* __restrict__ x,
                                                        const float* __restrict__ y,
                                                        float* __restrict__ out) {
    __shared__ float rbuf[3][NN];
    __shared__ float y2s[MM];
    const int b = blockIdx.x;
    const int i = threadIdx.x;

    const float* xrow  = x + ((size_t)b * NN + i) * KK;
    const float* ybase = y + (size_t)b * MM * KK;

    float xr[KK];
    float x2 = 0.f;
#pragma unroll
    for (int k = 0; k < KK; k += 4) {
        const float4 v = *(const float4*)(xrow + k);
        xr[k] = v.x; xr[k + 1] = v.y; xr[k + 2] = v.z; xr[k + 3] = v.w;
        x2 = fmaf(v.x, v.x, fmaf(v.y, v.y, fmaf(v.z, v.z, fmaf(v.w, v.w, x2))));
    }
    {
        const float* yrow = ybase + (size_t)i * KK;
        float s = 0.f;
#pragma unroll
        for (int k = 0; k < KK; k += 4) {
            const float4 v = *(const float4*)(yrow + k);
            s = fmaf(v.x, v.x, s); s = fmaf(v.y, v.y, s);
            s = fmaf(v.z, v.z, s); s = fmaf(v.w, v.w, s);
        }
        y2s[i] = s;
    }
    rbuf[0][i] = LARGE_F;
    rbuf[1][i] = LARGE_F;
    rbuf[2][i] = LARGE_F;

    float* row_w  = rbuf[0];
    float* row_p  = rbuf[2];
    float* row_p2 = rbuf[1];
    __syncthreads();

    float cur = LARGE_F;
    for (int p = 0; p < NDIAG; ++p) {
        const int j0 = p - i;
        const bool valid = (j0 >= 0) && (j0 < MM);
        float dg = 0.f;
        if (valid) {
            const float* yrow = ybase + (size_t)j0 * KK;
            float dot = 0.f;
#pragma unroll
            for (int k = 0; k < KK; k += 4) {
                const float4 v = *(const float4*)(yrow + k);
                dot = fmaf(xr[k], v.x, dot);
                dot = fmaf(xr[k + 1], v.y, dot);
                dot = fmaf(xr[k + 2], v.z, dot);
                dot = fmaf(xr[k + 3], v.w, dot);
            }
            dg = x2 + y2s[j0] - 2.f * dot;
        }
        const float r_w  = row_p[i];
        const float r_n  = (i > 0) ? row_p[i - 1] : LARGE_F;
        const float r_nw = (i > 0) ? row_p2[i - 1] : ((p == 0) ? 0.f : LARGE_F);

        const float m = fminf(fminf(r_nw, r_n), r_w);
        const float s = __expf(m - r_nw) + __expf(m - r_n) + __expf(m - r_w);
        const float softmin = m - __logf(s);

        cur = valid ? (dg + softmin) : LARGE_F;
        row_w[i] = cur;
        __syncthreads();

        float* tmp = row_w;
        row_w = row_p2; row_p2 = row_p; row_p = tmp;
    }
    if (i == NN - 1) out[b] = cur;
}

extern "C" void kernel_launch(void* const* d_in, const int* in_sizes, int n_in,
                              void* d_out, int out_size, void* d_ws, size_t ws_size,
                              hipStream_t stream) {
    const float* x = (const float*)d_in[0];
    const float* y = (const float*)d_in[1];
    float* out = (float*)d_out;

    const size_t need = (size_t)BB * CELLS * sizeof(float);  // 134,217,728 B
    if (ws_size >= need) {
        float* Dws = (float*)d_ws;
        sdtw_dist<<<dim3(64, BB), 256, 0, stream>>>(x, y, Dws);
        sdtw_dp<<<dim3(BB), 64, 0, stream>>>(Dws, out);
    } else {
        sdtw_fused_naive<<<dim3(BB), 512, 0, stream>>>(x, y, out);
    }
}

// Round 3
// 668.844 us; speedup vs baseline: 1.4084x; 1.1830x over previous
//
#include <hip/hip_runtime.h>

#define LARGE_F 1e30f
#define LOG2E_F 1.4426950408889634f
#define LN2_F   0.6931471805599453f

constexpr int BB = 128;
constexpr int NN = 512;
constexpr int MM = 512;
constexpr int KK = 64;
constexpr int NDIAG = NN + MM - 1;   // 1023
constexpr int PCELLS = 263680;       // padded (4-float-aligned) cells per batch

// ---- 4-float-aligned antidiagonal slot layout -------------------------------
// Diag p stores rows [imin4(p) .. imax(p)] at Db[slot_off(p) + i - imin4(p)].
// slot_off(p) and imin4(p) are multiples of 4 -> per-lane float4 reads at
// base = slot_off(p) - imin4(p) + 8*lane are 16B-aligned.
__device__ __forceinline__ int slot_off(int p) {
    if (p < NN) { const int a = p >> 2, r = p & 3; return ((a + 1) * (2 * a + r)) << 2; }
    const int t = p - NN, a = t >> 2, r = t & 3;
    return 132096 + (t << 9) - ((a * (2 * a + r - 1)) << 2);
}
__device__ __forceinline__ int imin4(int p) {
    return (p < NN) ? 0 : ((p - (NN - 1)) & ~3);
}
__device__ __forceinline__ int read_base(int p) { return slot_off(p) - imin4(p); }

// lane i <- lane i-1 via DPP wave_shr:1 (2-cycle VALU, no LDS round-trip).
__device__ __forceinline__ float wave_shr1(float v, float bound) {
    const int r = __builtin_amdgcn_update_dpp(__float_as_int(bound), __float_as_int(v),
                                              0x138, 0xf, 0xf, false);
    return __int_as_float(r);
}

// ---------------- Phase 1: D[b,i,j] = ||x_i - y_j||^2 into aligned diag slots.
__global__ __launch_bounds__(256, 4) void sdtw_dist(const float* __restrict__ x,
                                                    const float* __restrict__ y,
                                                    float* __restrict__ Dws) {
    __shared__ float xs[64][68];
    __shared__ float ys[64][68];
    __shared__ float x2s[64];
    __shared__ float y2s[64];
    // D tile aliases xs after the k-loop. Pad 66: diagonal reads bank-stride 1.
    float (*dt)[66] = (float (*)[66])(&xs[0][0]);

    const int b  = blockIdx.y;
    const int ti = (blockIdx.x >> 3) << 6;
    const int tj = (blockIdx.x & 7) << 6;
    const int t  = threadIdx.x;

    const float* xb = x + ((size_t)b * NN + ti) * KK;
    const float* yb = y + ((size_t)b * MM + tj) * KK;

    {
        const int r0 = t >> 4;
        const int c0 = (t & 15) << 2;
#pragma unroll
        for (int q = 0; q < 4; ++q) {
            const int r = r0 + (q << 4);
            const float4 xv = *(const float4*)(xb + r * KK + c0);
            const float4 yv = *(const float4*)(yb + r * KK + c0);
            *(float4*)(&xs[r][c0]) = xv;
            *(float4*)(&ys[r][c0]) = yv;
        }
    }
    __syncthreads();

    if (t < 128) {
        const int r = t & 63;
        const float* row = (t < 64) ? &xs[r][0] : &ys[r][0];
        float s = 0.f;
#pragma unroll
        for (int k = 0; k < KK; k += 4) {
            const float4 v = *(const float4*)(row + k);
            s = fmaf(v.x, v.x, s); s = fmaf(v.y, v.y, s);
            s = fmaf(v.z, v.z, s); s = fmaf(v.w, v.w, s);
        }
        if (t < 64) x2s[r] = s; else y2s[r] = s;
    }
    __syncthreads();

    const int ty = t >> 4;
    const int tx = t & 15;

    float acc[4][4] = {};
    for (int k0 = 0; k0 < KK; k0 += 4) {
        float4 xa[4], yv[4];
#pragma unroll
        for (int a = 0; a < 4; ++a) xa[a] = *(const float4*)(&xs[(a << 4) + ty][k0]);
#pragma unroll
        for (int c = 0; c < 4; ++c) yv[c] = *(const float4*)(&ys[(c << 4) + tx][k0]);
#pragma unroll
        for (int a = 0; a < 4; ++a) {
#pragma unroll
            for (int c = 0; c < 4; ++c) {
                acc[a][c] = fmaf(xa[a].x, yv[c].x, acc[a][c]);
                acc[a][c] = fmaf(xa[a].y, yv[c].y, acc[a][c]);
                acc[a][c] = fmaf(xa[a].z, yv[c].z, acc[a][c]);
                acc[a][c] = fmaf(xa[a].w, yv[c].w, acc[a][c]);
            }
        }
    }
    __syncthreads();   // done reading xs -> safe to alias as dt

#pragma unroll
    for (int a = 0; a < 4; ++a) {
        const float xx = x2s[(a << 4) + ty];
#pragma unroll
        for (int c = 0; c < 4; ++c) {
            dt[(a << 4) + ty][(c << 4) + tx] = xx + y2s[(c << 4) + tx] - 2.f * acc[a][c];
        }
    }
    __syncthreads();

    // Diagonal-ordered write-out: each tile diagonal is one contiguous run.
    {
        const int w    = t >> 6;
        const int lane = t & 63;
        float* Db = Dws + (size_t)b * PCELLS;
        for (int q = w; q < 127; q += 4) {
            const int i_lo = (q > 63) ? (q - 63) : 0;
            const int i_hi = (q < 63) ? q : 63;
            const int len  = i_hi - i_lo + 1;
            if (lane < len) {
                const int il = i_lo + lane;
                const int p  = ti + tj + q;
                Db[slot_off(p) + (ti + il) - imin4(p)] = dt[il][q - il];
            }
        }
    }
}

// ---------------- Phase 2: one wave per batch, 8 rows/lane, all-register DP.
// Depth-8 prefetch ring hides HBM/LLC latency; DPP wave_shr:1 for the row
// boundary; invalid cells self-propagate ~1e30 (no per-cell masking needed).
__global__ __launch_bounds__(64) void sdtw_dp(const float* __restrict__ Dws,
                                              float* __restrict__ out) {
    const int b    = blockIdx.x;
    const int lane = threadIdx.x;
    const float* __restrict__ Db = Dws + (size_t)b * PCELLS;

    float A[8], Bv[8];
    float d[8][8];                       // prefetch ring (statically indexed)
#pragma unroll
    for (int c = 0; c < 8; ++c) { A[c] = LARGE_F; Bv[c] = LARGE_F; }

#pragma unroll
    for (int s = 0; s < 8; ++s) {
        const float4* p4 = (const float4*)(Db + read_base(s) + 8 * lane);
        const float4 u0 = p4[0], u1 = p4[1];
        d[s][0] = u0.x; d[s][1] = u0.y; d[s][2] = u0.z; d[s][3] = u0.w;
        d[s][4] = u1.x; d[s][5] = u1.y; d[s][6] = u1.z; d[s][7] = u1.w;
    }

    auto dp_step = [&](int p_, float (&P)[8], float (&P2)[8], float (&DB)[8]) {
        float shp  = wave_shr1(P[7],  LARGE_F);
        float shp2 = wave_shr1(P2[7], LARGE_F);
        if (p_ == 0 && lane == 0) shp2 = 0.f;
#pragma unroll
        for (int c = 7; c >= 0; --c) {     // descending: in-place P2 overwrite
            const float w  = P[c];
            const float n  = (c == 0) ? shp  : P[c - 1];
            const float nw = (c == 0) ? shp2 : P2[c - 1];
            const float mn = fminf(fminf(w, n), nw);
            const float mx = fmaxf(fmaxf(w, n), nw);
            const float md = __builtin_amdgcn_fmed3f(w, n, nw);
            const float sm = mn - log2f(1.0f + exp2f(mn - md) + exp2f(mn - mx));
            P2[c] = fmaf(DB[c], LOG2E_F, sm);
        }
        const int pn = p_ + 8;             // refill ring slot with diag p+8
        if (pn < NDIAG) {
            const float4* p4 = (const float4*)(Db + read_base(pn) + 8 * lane);
            const float4 u0 = p4[0], u1 = p4[1];
            DB[0] = u0.x; DB[1] = u0.y; DB[2] = u0.z; DB[3] = u0.w;
            DB[4] = u1.x; DB[5] = u1.y; DB[6] = u1.z; DB[7] = u1.w;
        }
    };

#pragma unroll 1
    for (int pb = 0; pb < 1024; pb += 8) {
#pragma unroll
        for (int s = 0; s < 8; s += 2) {
            dp_step(pb + s,     A,  Bv, d[s]);
            dp_step(pb + s + 1, Bv, A,  d[s + 1]);
        }
    }
    // R'_1022 lives in Bv; cell (511,511) is lane 63, c=7. Undo log2e scaling.
    if (lane == 63) out[b] = Bv[7] * LN2_F;
}

// ---------------- Fallback (only if ws too small): fused, correct, slow.
__global__ __launch_bounds__(512) void sdtw_fused_naive(const float* __restrict__ x,
                                                        const float* __restrict__ y,
                                                        float* __restrict__ out) {
    __shared__ float rbuf[3][NN];
    __shared__ float y2s[MM];
    const int b = blockIdx.x;
    const int i = threadIdx.x;

    const float* xrow  = x + ((size_t)b * NN + i) * KK;
    const float* ybase = y + (size_t)b * MM * KK;

    float xr[KK];
    float x2 = 0.f;
#pragma unroll
    for (int k = 0; k < KK; k += 4) {
        const float4 v = *(const float4*)(xrow + k);
        xr[k] = v.x; xr[k + 1] = v.y; xr[k + 2] = v.z; xr[k + 3] = v.w;
        x2 = fmaf(v.x, v.x, fmaf(v.y, v.y, fmaf(v.z, v.z, fmaf(v.w, v.w, x2))));
    }
    {
        const float* yrow = ybase + (size_t)i * KK;
        float s = 0.f;
#pragma unroll
        for (int k = 0; k < KK; k += 4) {
            const float4 v = *(const float4*)(yrow + k);
            s = fmaf(v.x, v.x, s); s = fmaf(v.y, v.y, s);
            s = fmaf(v.z, v.z, s); s = fmaf(v.w, v.w, s);
        }
        y2s[i] = s;
    }
    rbuf[0][i] = LARGE_F;
    rbuf[1][i] = LARGE_F;
    rbuf[2][i] = LARGE_F;

    float* row_w  = rbuf[0];
    float* row_p  = rbuf[2];
    float* row_p2 = rbuf[1];
    __syncthreads();

    float cur = LARGE_F;
    for (int p = 0; p < NDIAG; ++p) {
        const int j0 = p - i;
        const bool valid = (j0 >= 0) && (j0 < MM);
        float dg = 0.f;
        if (valid) {
            const float* yrow = ybase + (size_t)j0 * KK;
            float dot = 0.f;
#pragma unroll
            for (int k = 0; k < KK; k += 4) {
                const float4 v = *(const float4*)(yrow + k);
                dot = fmaf(xr[k], v.x, dot);
                dot = fmaf(xr[k + 1], v.y, dot);
                dot = fmaf(xr[k + 2], v.z, dot);
                dot = fmaf(xr[k + 3], v.w, dot);
            }
            dg = x2 + y2s[j0] - 2.f * dot;
        }
        const float r_w  = row_p[i];
        const float r_n  = (i > 0) ? row_p[i - 1] : LARGE_F;
        const float r_nw = (i > 0) ? row_p2[i - 1] : ((p == 0) ? 0.f : LARGE_F);

        const float m = fminf(fminf(r_nw, r_n), r_w);
        const float s = __expf(m - r_nw) + __expf(m - r_n) + __expf(m - r_w);
        const float softmin = m - __logf(s);

        cur = valid ? (dg + softmin) : LARGE_F;
        row_w[i] = cur;
        __syncthreads();

        float* tmp = row_w;
        row_w = row_p2; row_p2 = row_p; row_p = tmp;
    }
    if (i == NN - 1) out[b] = cur;
}

extern "C" void kernel_launch(void* const* d_in, const int* in_sizes, int n_in,
                              void* d_out, int out_size, void* d_ws, size_t ws_size,
                              hipStream_t stream) {
    const float* x = (const float*)d_in[0];
    const float* y = (const float*)d_in[1];
    float* out = (float*)d_out;

    const size_t need = (size_t)BB * PCELLS * sizeof(float);  // 135,004,160 B
    if (ws_size >= need) {
        float* Dws = (float*)d_ws;
        sdtw_dist<<<dim3(64, BB), 256, 0, stream>>>(x, y, Dws);
        sdtw_dp<<<dim3(BB), 64, 0, stream>>>(Dws, out);
    } else {
        sdtw_fused_naive<<<dim3(BB), 512, 0, stream>>>(x, y, out);
    }
}

// Round 4
// 611.594 us; speedup vs baseline: 1.5402x; 1.0936x over previous
//
#include <hip/hip_runtime.h>

#define LARGE_F 1e30f
#define LOG2E_F 1.4426950408889634f
#define LN2_F   0.6931471805599453f

constexpr int BB = 128;
constexpr int NN = 512;
constexpr int MM = 512;
constexpr int KK = 64;
constexpr int NDIAG = NN + MM - 1;   // 1023
constexpr int PCELLS = 263680;       // padded (4-float-aligned) cells per batch

// ---- 4-float-aligned antidiagonal slot layout -------------------------------
__device__ __forceinline__ int slot_off(int p) {
    if (p < NN) { const int a = p >> 2, r = p & 3; return ((a + 1) * (2 * a + r)) << 2; }
    const int t = p - NN, a = t >> 2, r = t & 3;
    return 132096 + (t << 9) - ((a * (2 * a + r - 1)) << 2);
}
__device__ __forceinline__ int imin4(int p) {
    return (p < NN) ? 0 : ((p - (NN - 1)) & ~3);
}
__device__ __forceinline__ int read_base(int p) { return slot_off(p) - imin4(p); }

// lane i <- lane i-1 via DPP wave_shr:1 (VALU, no LDS round-trip).
__device__ __forceinline__ float wave_shr1(float v, float bound) {
    const int r = __builtin_amdgcn_update_dpp(__float_as_int(bound), __float_as_int(v),
                                              0x138, 0xf, 0xf, false);
    return __int_as_float(r);
}

// ---------------- Phase 1: D[b,i,j] = ||x_i - y_j||^2 into aligned diag slots.
__global__ __launch_bounds__(256, 4) void sdtw_dist(const float* __restrict__ x,
                                                    const float* __restrict__ y,
                                                    float* __restrict__ Dws) {
    __shared__ float xs[64][68];
    __shared__ float ys[64][68];
    __shared__ float x2s[64];
    __shared__ float y2s[64];
    float (*dt)[66] = (float (*)[66])(&xs[0][0]);   // alias after k-loop

    const int b  = blockIdx.y;
    const int ti = (blockIdx.x >> 3) << 6;
    const int tj = (blockIdx.x & 7) << 6;
    const int t  = threadIdx.x;

    const float* xb = x + ((size_t)b * NN + ti) * KK;
    const float* yb = y + ((size_t)b * MM + tj) * KK;

    {
        const int r0 = t >> 4;
        const int c0 = (t & 15) << 2;
#pragma unroll
        for (int q = 0; q < 4; ++q) {
            const int r = r0 + (q << 4);
            const float4 xv = *(const float4*)(xb + r * KK + c0);
            const float4 yv = *(const float4*)(yb + r * KK + c0);
            *(float4*)(&xs[r][c0]) = xv;
            *(float4*)(&ys[r][c0]) = yv;
        }
    }
    __syncthreads();

    if (t < 128) {
        const int r = t & 63;
        const float* row = (t < 64) ? &xs[r][0] : &ys[r][0];
        float s = 0.f;
#pragma unroll
        for (int k = 0; k < KK; k += 4) {
            const float4 v = *(const float4*)(row + k);
            s = fmaf(v.x, v.x, s); s = fmaf(v.y, v.y, s);
            s = fmaf(v.z, v.z, s); s = fmaf(v.w, v.w, s);
        }
        if (t < 64) x2s[r] = s; else y2s[r] = s;
    }
    __syncthreads();

    const int ty = t >> 4;
    const int tx = t & 15;

    float acc[4][4] = {};
    for (int k0 = 0; k0 < KK; k0 += 4) {
        float4 xa[4], yv[4];
#pragma unroll
        for (int a = 0; a < 4; ++a) xa[a] = *(const float4*)(&xs[(a << 4) + ty][k0]);
#pragma unroll
        for (int c = 0; c < 4; ++c) yv[c] = *(const float4*)(&ys[(c << 4) + tx][k0]);
#pragma unroll
        for (int a = 0; a < 4; ++a) {
#pragma unroll
            for (int c = 0; c < 4; ++c) {
                acc[a][c] = fmaf(xa[a].x, yv[c].x, acc[a][c]);
                acc[a][c] = fmaf(xa[a].y, yv[c].y, acc[a][c]);
                acc[a][c] = fmaf(xa[a].z, yv[c].z, acc[a][c]);
                acc[a][c] = fmaf(xa[a].w, yv[c].w, acc[a][c]);
            }
        }
    }
    __syncthreads();

#pragma unroll
    for (int a = 0; a < 4; ++a) {
        const float xx = x2s[(a << 4) + ty];
#pragma unroll
        for (int c = 0; c < 4; ++c) {
            dt[(a << 4) + ty][(c << 4) + tx] = xx + y2s[(c << 4) + tx] - 2.f * acc[a][c];
        }
    }
    __syncthreads();

    {
        const int w    = t >> 6;
        const int lane = t & 63;
        float* Db = Dws + (size_t)b * PCELLS;
        for (int q = w; q < 127; q += 4) {
            const int i_lo = (q > 63) ? (q - 63) : 0;
            const int i_hi = (q < 63) ? q : 63;
            const int len  = i_hi - i_lo + 1;
            if (lane < len) {
                const int il = i_lo + lane;
                const int p  = ti + tj + q;
                Db[slot_off(p) + (ti + il) - imin4(p)] = dt[il][q - il];
            }
        }
    }
}

// ---------------- Phase 2: one wave per batch, 8 rows/lane, all-register DP.
// Two 8-deep prefetch rings, branch-free group issue (clamped diag index) so
// the compiler keeps 16 loads in flight with counted waitcnts.
__global__ __launch_bounds__(64, 1) void sdtw_dp(const float* __restrict__ Dws,
                                                 float* __restrict__ out) {
    const int b    = blockIdx.x;
    const int lane = threadIdx.x;
    const float* __restrict__ Db = Dws + (size_t)b * PCELLS;

    float A[8], Bv[8];
    float dA[8][8], dB[8][8];            // double-buffered prefetch rings
#pragma unroll
    for (int c = 0; c < 8; ++c) { A[c] = LARGE_F; Bv[c] = LARGE_F; }

    // Branch-free diag load: clamp to the last real diagonal (1022). Clamped
    // slots are never consumed; all clamped addresses stay inside PCELLS.
    auto load_diag = [&](int pd, float (&DBUF)[8]) {
        const int pc = (pd < NDIAG - 1) ? pd : (NDIAG - 1);
        const float4* p4 = (const float4*)(Db + read_base(pc) + 8 * lane);
        const float4 u0 = p4[0], u1 = p4[1];
        DBUF[0] = u0.x; DBUF[1] = u0.y; DBUF[2] = u0.z; DBUF[3] = u0.w;
        DBUF[4] = u1.x; DBUF[5] = u1.y; DBUF[6] = u1.z; DBUF[7] = u1.w;
    };

    auto dp_step = [&](int p_, float (&P)[8], float (&P2)[8], float (&DBUF)[8]) {
        float shp  = wave_shr1(P[7],  LARGE_F);
        float shp2 = wave_shr1(P2[7], LARGE_F);
        if (p_ == 0 && lane == 0) shp2 = 0.f;
#pragma unroll
        for (int c = 7; c >= 0; --c) {       // descending: in-place P2 overwrite
            const float w  = P[c];
            const float n  = (c == 0) ? shp  : P[c - 1];
            const float nw = (c == 0) ? shp2 : P2[c - 1];
            const float mn = fminf(fminf(w, n), nw);
            const float mx = fmaxf(fmaxf(w, n), nw);
            const float md = __builtin_amdgcn_fmed3f(w, n, nw);
            const float sm = mn - log2f(1.0f + exp2f(mn - md) + exp2f(mn - mx));
            P2[c] = fmaf(DBUF[c], LOG2E_F, sm);
        }
    };

    // Prologue: ring A <- diags 0..7.
#pragma unroll
    for (int s = 0; s < 8; ++s) load_diag(s, dA[s]);

#pragma unroll 1
    for (int pb = 0; pb < 1024; pb += 16) {
        // Issue next 8 diags into ring B, then compute ring A.
#pragma unroll
        for (int s = 0; s < 8; ++s) load_diag(pb + 8 + s, dB[s]);
#pragma unroll
        for (int s = 0; s < 8; s += 2) {
            dp_step(pb + s,     A,  Bv, dA[s]);
            dp_step(pb + s + 1, Bv, A,  dA[s + 1]);
        }
        // Issue the following 8 diags into ring A, then compute ring B.
#pragma unroll
        for (int s = 0; s < 8; ++s) load_diag(pb + 16 + s, dA[s]);
#pragma unroll
        for (int s = 0; s < 8; s += 2) {
            dp_step(pb + 8 + s,     A,  Bv, dB[s]);
            dp_step(pb + 8 + s + 1, Bv, A,  dB[s + 1]);
        }
    }
    // Step 1022 (even) wrote R'_1022 into Bv; cell (511,511) = lane 63, c=7.
    if (lane == 63) out[b] = Bv[7] * LN2_F;
}

// ---------------- Fallback (only if ws too small): fused, correct, slow.
__global__ __launch_bounds__(512) void sdtw_fused_naive(const float* __restrict__ x,
                                                        const float* __restrict__ y,
                                                        float* __restrict__ out) {
    __shared__ float rbuf[3][NN];
    __shared__ float y2s[MM];
    const int b = blockIdx.x;
    const int i = threadIdx.x;

    const float* xrow  = x + ((size_t)b * NN + i) * KK;
    const float* ybase = y + (size_t)b * MM * KK;

    float xr[KK];
    float x2 = 0.f;
#pragma unroll
    for (int k = 0; k < KK; k += 4) {
        const float4 v = *(const float4*)(xrow + k);
        xr[k] = v.x; xr[k + 1] = v.y; xr[k + 2] = v.z; xr[k + 3] = v.w;
        x2 = fmaf(v.x, v.x, fmaf(v.y, v.y, fmaf(v.z, v.z, fmaf(v.w, v.w, x2))));
    }
    {
        const float* yrow = ybase + (size_t)i * KK;
        float s = 0.f;
#pragma unroll
        for (int k = 0; k < KK; k += 4) {
            const float4 v = *(const float4*)(yrow + k);
            s = fmaf(v.x, v.x, s); s = fmaf(v.y, v.y, s);
            s = fmaf(v.z, v.z, s); s = fmaf(v.w, v.w, s);
        }
        y2s[i] = s;
    }
    rbuf[0][i] = LARGE_F;
    rbuf[1][i] = LARGE_F;
    rbuf[2][i] = LARGE_F;

    float* row_w  = rbuf[0];
    float* row_p  = rbuf[2];
    float* row_p2 = rbuf[1];
    __syncthreads();

    float cur = LARGE_F;
    for (int p = 0; p < NDIAG; ++p) {
        const int j0 = p - i;
        const bool valid = (j0 >= 0) && (j0 < MM);
        float dg = 0.f;
        if (valid) {
            const float* yrow = ybase + (size_t)j0 * KK;
            float dot = 0.f;
#pragma unroll
            for (int k = 0; k < KK; k += 4) {
                const float4 v = *(const float4*)(yrow + k);
                dot = fmaf(xr[k], v.x, dot);
                dot = fmaf(xr[k + 1], v.y, dot);
                dot = fmaf(xr[k + 2], v.z, dot);
                dot = fmaf(xr[k + 3], v.w, dot);
            }
            dg = x2 + y2s[j0] - 2.f * dot;
        }
        const float r_w  = row_p[i];
        const float r_n  = (i > 0) ? row_p[i - 1] : LARGE_F;
        const float r_nw = (i > 0) ? row_p2[i - 1] : ((p == 0) ? 0.f : LARGE_F);

        const float m = fminf(fminf(r_nw, r_n), r_w);
        const float s = __expf(m - r_nw) + __expf(m - r_n) + __expf(m - r_w);
        const float softmin = m - __logf(s);

        cur = valid ? (dg + softmin) : LARGE_F;
        row_w[i] = cur;
        __syncthreads();

        float* tmp = row_w;
        row_w = row_p2; row_p2 = row_p; row_p = tmp;
    }
    if (i == NN - 1) out[b] = cur;
}

extern "C" void kernel_launch(void* const* d_in, const int* in_sizes, int n_in,
                              void* d_out, int out_size, void* d_ws, size_t ws_size,
                              hipStream_t stream) {
    const float* x = (const float*)d_in[0];
    const float* y = (const float*)d_in[1];
    float* out = (float*)d_out;

    const size_t need = (size_t)BB * PCELLS * sizeof(float);  // 135,004,160 B
    if (ws_size >= need) {
        float* Dws = (float*)d_ws;
        sdtw_dist<<<dim3(64, BB), 256, 0, stream>>>(x, y, Dws);
        sdtw_dp<<<dim3(BB), 64, 0, stream>>>(Dws, out);
    } else {
        sdtw_fused_naive<<<dim3(BB), 512, 0, stream>>>(x, y, out);
    }
}